// Round 5
// baseline (477.716 us; speedup 1.0000x reference)
//
#include <hip/hip_runtime.h>
#include <hip/hip_bf16.h>
#include <stdint.h>

#define B_ 1024
#define T_ 255
#define D_ 128
#define G_ 512   // 4*H

typedef float f32x4 __attribute__((ext_vector_type(4)));
typedef short s16x8 __attribute__((ext_vector_type(8)));
typedef unsigned u32x4 __attribute__((ext_vector_type(4)));

__device__ __forceinline__ unsigned pk2(float a, float b){
  __hip_bfloat162 h2 = __float22bfloat162_rn(make_float2(a, b));  // v_cvt_pk_bf16_f32
  union { __hip_bfloat162 h; unsigned u; } c; c.h = h2; return c.u;
}
__device__ __forceinline__ unsigned short bf1(float a){
  __hip_bfloat16 h = __float2bfloat16(a);
  union { __hip_bfloat16 h; unsigned short u; } c; c.h = h; return c.u;
}
__device__ __forceinline__ float blo(unsigned u){ union{unsigned u;float f;}c; c.u = u << 16; return c.f; }
__device__ __forceinline__ float bhi(unsigned u){ union{unsigned u;float f;}c; c.u = u & 0xffff0000u; return c.f; }
__device__ __forceinline__ float sigm_f(float x){
  return __builtin_amdgcn_rcpf(1.f + __expf(-x));
}
__device__ __forceinline__ float tanh_f2(float x){
  return fmaf(-2.f, __builtin_amdgcn_rcpf(1.f + __expf(2.f * x)), 1.f);
}

// ---------------- Kernel 1: softmax(x_part) ; out_w = attn*x ------------------
__global__ __launch_bounds__(512) void k_attn(const float* __restrict__ x,
    const float* __restrict__ Wa, float* __restrict__ out_w){
  extern __shared__ float4 xs4[];          // 8160 float4 = 130560 B
  __shared__ float wxs[256];
  __shared__ float part_s[16][128];
  __shared__ float red[128];
  __shared__ float attn_s[128];
  int tid = threadIdx.x, b = blockIdx.x;
  if (tid < T_) wxs[tid] = Wa[2 * D_ + tid];
  __syncthreads();
  const float4* xg = (const float4*)(x + (size_t)b * T_ * D_);
  float4 acc = {0.f, 0.f, 0.f, 0.f};
  for (int i = tid; i < 8160; i += 512){
    float4 v = xg[i];
    xs4[i] = v;
    float wt = wxs[i >> 5];
    acc.x += v.x * wt; acc.y += v.y * wt; acc.z += v.z * wt; acc.w += v.w * wt;
  }
  int d0 = (tid & 31) * 4, s = tid >> 5;
  *(float4*)&part_s[s][d0] = acc;
  __syncthreads();
  if (tid < 128){
    float v = 0.f;
    #pragma unroll
    for (int k = 0; k < 16; k++) v += part_s[k][tid];
    red[tid] = v; attn_s[tid] = v;
  }
  __syncthreads();
  for (int st = 64; st >= 1; st >>= 1){
    if (tid < st) red[tid] = fmaxf(red[tid], red[tid + st]);
    __syncthreads();
  }
  float mx = red[0];
  __syncthreads();
  float ev = 0.f;
  if (tid < 128){ ev = __expf(attn_s[tid] - mx); red[tid] = ev; }
  __syncthreads();
  for (int st = 64; st >= 1; st >>= 1){
    if (tid < st) red[tid] += red[tid + st];
    __syncthreads();
  }
  float sm = red[0];
  if (tid < 128) attn_s[tid] = ev / sm;
  __syncthreads();
  float4 at = *(const float4*)&attn_s[d0];
  float4* owg = (float4*)(out_w + (size_t)b * T_ * D_);
  for (int i = tid; i < 8160; i += 512){
    float4 v = xs4[i];
    float4 wv; wv.x = v.x*at.x; wv.y = v.y*at.y; wv.z = v.z*at.z; wv.w = v.w*at.w;
    owg[i] = wv;
  }
}

// ---------------- Kernel 2: G1 = wx@W_ih^T + b_ih + b_hh, lane-packed bf16 ----
// grid 1024 = 64 row-groups(16 b) x 16 t-chunks(16 t). 512 thr = 8 waves.
// wave w: cols n = g*128 + w*16 + l15 (4 gates, d-slice w).
// G1 layout (uint2): [t][bg(=b>>1)][w][a = (b&1)*16 + l15] ; q = {(i,f),(g,o)}.
__global__ __launch_bounds__(512, 2) void k_gemm1(const float* __restrict__ wx,
    const float* __restrict__ W_ih, const float* __restrict__ b_ih,
    const float* __restrict__ b_hh, uint2* __restrict__ g1p){
  int tid = threadIdx.x;
  int lane = tid & 63, w = tid >> 6;
  int l15 = lane & 15, lg = lane >> 4;
  int bx = blockIdx.x;
  int bg16 = bx & 63, tc = bx >> 6;
  int row0 = bg16 << 4;

  // W_ih B-fragments [kt][gate], k = kt*32 + lg*8 + j; bias folded into acc init
  s16x8 fih[4][4];
  float bias[4];
  #pragma unroll
  for (int g = 0; g < 4; g++){
    int n = g * 128 + w * 16 + l15;
    bias[g] = b_ih[n] + b_hh[n];
    #pragma unroll
    for (int kt = 0; kt < 4; kt++){
      const float4* p1 = (const float4*)(W_ih + n * D_ + kt * 32 + lg * 8);
      float4 a0 = p1[0], a1 = p1[1];
      u32x4 bv;
      bv[0] = pk2(a0.x, a0.y); bv[1] = pk2(a0.z, a0.w);
      bv[2] = pk2(a1.x, a1.y); bv[3] = pk2(a1.z, a1.w);
      fih[kt][g] = __builtin_bit_cast(s16x8, bv);
    }
  }
  const float* xa = wx + ((size_t)(row0 + l15) * T_ + (size_t)tc * 16) * D_;
  int tmax = T_ - tc * 16; if (tmax > 16) tmax = 16;
  for (int i = 0; i < tmax; i++){
    int t = tc * 16 + i;
    s16x8 af[4];
    #pragma unroll
    for (int kt = 0; kt < 4; kt++){
      const float4* xp4 = (const float4*)(xa + (size_t)i * D_ + kt * 32 + lg * 8);
      float4 x0 = xp4[0], x1 = xp4[1];
      u32x4 av;
      av[0] = pk2(x0.x, x0.y); av[1] = pk2(x0.z, x0.w);
      av[2] = pk2(x1.x, x1.y); av[3] = pk2(x1.z, x1.w);
      af[kt] = __builtin_bit_cast(s16x8, av);
    }
    f32x4 ac0 = {bias[0], bias[0], bias[0], bias[0]};
    f32x4 ac1 = {bias[1], bias[1], bias[1], bias[1]};
    f32x4 ac2 = {bias[2], bias[2], bias[2], bias[2]};
    f32x4 ac3 = {bias[3], bias[3], bias[3], bias[3]};
    #pragma unroll
    for (int kt = 0; kt < 4; kt++){
      ac0 = __builtin_amdgcn_mfma_f32_16x16x32_bf16(af[kt], fih[kt][0], ac0, 0,0,0);
      ac1 = __builtin_amdgcn_mfma_f32_16x16x32_bf16(af[kt], fih[kt][1], ac1, 0,0,0);
      ac2 = __builtin_amdgcn_mfma_f32_16x16x32_bf16(af[kt], fih[kt][2], ac2, 0,0,0);
      ac3 = __builtin_amdgcn_mfma_f32_16x16x32_bf16(af[kt], fih[kt][3], ac3, 0,0,0);
    }
    #pragma unroll
    for (int r = 0; r < 4; r++){
      int b = row0 + lg * 4 + r;
      int j = b & 1, bgr = b >> 1;
      uint2 q;
      q.x = pk2(ac0[r], ac1[r]);     // (i, f)
      q.y = pk2(ac2[r], ac3[r]);     // (g, o)
      g1p[((size_t)t * 512 + bgr) * 256 + w * 32 + j * 16 + l15] = q;
    }
  }
}

// ---------------- Kernel 3: recurrence. 512 blocks x 2 rows x 512 thr ---------
// 2 blocks/CU (W_hh-only weights keep VGPR<=128). Batch row j at A M-row 8j;
// C row = lg*4+r -> own lanes (lg even, r=0): 1 cell/lane for 32/64 lanes.
__global__ __launch_bounds__(512, 4) void k_rnn(const float* __restrict__ W_hh,
    const uint2* __restrict__ g1p, float* __restrict__ out_e){
  __shared__ char hl[1024];   // h bf16 [2][2][128], byte ^= (row<<4) swizzle
  int tid = threadIdx.x;
  int lane = tid & 63, w = tid >> 6;
  int l15 = lane & 15, lg = lane >> 4;
  int bg = blockIdx.x;                 // rows {2bg, 2bg+1}
  int d = w * 16 + l15;
  int hr = l15 >> 3;                   // h row this lane reads (x8 replication)

  // W_hh B-fragments [kt][gate]
  s16x8 fhh[4][4];
  #pragma unroll
  for (int g = 0; g < 4; g++){
    int n = g * 128 + w * 16 + l15;
    #pragma unroll
    for (int kt = 0; kt < 4; kt++){
      const float4* p2 = (const float4*)(W_hh + n * D_ + kt * 32 + lg * 8);
      float4 c0v = p2[0], c1v = p2[1];
      u32x4 cv;
      cv[0] = pk2(c0v.x, c0v.y); cv[1] = pk2(c0v.z, c0v.w);
      cv[2] = pk2(c1v.x, c1v.y); cv[3] = pk2(c1v.z, c1v.w);
      fhh[kt][g] = __builtin_bit_cast(s16x8, cv);
    }
  }
  unsigned rd[4];
  #pragma unroll
  for (int kt = 0; kt < 4; kt++)
    rd[kt] = ((unsigned)(hr * 256 + kt * 64 + lg * 16)) ^ ((unsigned)hr << 4);
  bool own = (lg & 1) == 0;
  int j = lg >> 1;
  unsigned wr_ = ((unsigned)(j * 256 + d * 2)) ^ ((unsigned)j << 4);
  float* op = out_e + (size_t)(2 * bg + j) * T_ * D_ + d;
  float cst = 0.f;
  if (tid < 256) ((unsigned*)hl)[tid] = 0u;   // zero both h buffers (1 KB)

  // G1 stream: base + t*131072 (uint2 units); two advancing ptrs (even/odd t)
  const uint2* pa = g1p + (size_t)bg * 256 + w * 32 + j * 16 + l15;
  const uint2* pb = pa + 131072;
  uint2 qa = make_uint2(0,0), qb = make_uint2(0,0);
  if (own){ qa = pa[0]; qb = pb[0]; }
  __syncthreads();

#define STEP(Q, PP, RDOFF, WROFF, TT) do {                                          \
    s16x8 aa[4];                                                                    \
    _Pragma("unroll")                                                               \
    for (int kt = 0; kt < 4; kt++) aa[kt] = *(const s16x8*)(hl + rd[kt] + (RDOFF)); \
    f32x4 ac0 = {0.f,0.f,0.f,0.f}, ac1 = ac0, ac2 = ac0, ac3 = ac0;                 \
    _Pragma("unroll")                                                               \
    for (int kt = 0; kt < 4; kt++){                                                 \
      ac0 = __builtin_amdgcn_mfma_f32_16x16x32_bf16(aa[kt], fhh[kt][0], ac0,0,0,0); \
      ac1 = __builtin_amdgcn_mfma_f32_16x16x32_bf16(aa[kt], fhh[kt][1], ac1,0,0,0); \
      ac2 = __builtin_amdgcn_mfma_f32_16x16x32_bf16(aa[kt], fhh[kt][2], ac2,0,0,0); \
      ac3 = __builtin_amdgcn_mfma_f32_16x16x32_bf16(aa[kt], fhh[kt][3], ac3,0,0,0); \
    }                                                                               \
    if (own){                                                                       \
      float gi = blo(Q.x) + ac0[0], gf = bhi(Q.x) + ac1[0];                         \
      float gg = blo(Q.y) + ac2[0], go = bhi(Q.y) + ac3[0];                         \
      if ((TT) + 2 < T_){ PP += 262144; Q = PP[0]; }                                \
      float cn = fmaf(sigm_f(gf), cst, sigm_f(gi) * tanh_f2(gg));                   \
      float hn = sigm_f(go) * tanh_f2(cn); cst = cn;                                \
      *op = hn; op += D_;                                                           \
      *(unsigned short*)(hl + wr_ + (WROFF)) = bf1(hn);                             \
    }                                                                               \
    __syncthreads();                                                                \
  } while (0)

  for (int t = 0; t < T_ - 1; t += 2){
    STEP(qa, pa, 0, 512, t);        // even t: read h buf0, write buf1
    STEP(qb, pb, 512, 0, t + 1);    // odd  t: read buf1, write buf0
  }
  STEP(qa, pa, 0, 512, T_ - 1);     // t = 254 (even)
#undef STEP
}

extern "C" void kernel_launch(void* const* d_in, const int* in_sizes, int n_in,
                              void* d_out, int out_size, void* d_ws, size_t ws_size,
                              hipStream_t stream) {
  (void)in_sizes; (void)n_in; (void)out_size;
  const float* x    = (const float*)d_in[0];
  const float* Wa   = (const float*)d_in[1];
  // d_in[2] = ba : dead (softmax shift invariance); Wh/Wc parts of Wa also dead
  const float* W_ih = (const float*)d_in[3];
  const float* W_hh = (const float*)d_in[4];
  const float* b_ih = (const float*)d_in[5];
  const float* b_hh = (const float*)d_in[6];
  float* out_w = (float*)d_out;
  float* out_e = out_w + (size_t)B_ * T_ * D_;
  uint2* g1p = (uint2*)d_ws;                    // 255*512*256*8 B = 267.4 MB
  size_t need = (size_t)T_ * 512 * 256 * 8;
  if (ws_size < need) return;

  k_attn <<<B_, 512, 130560, stream>>>(x, Wa, out_w);
  k_gemm1<<<1024, 512, 0, stream>>>(out_w, W_ih, b_ih, b_hh, g1p);
  k_rnn  <<<512, 512, 0, stream>>>(W_hh, g1p, out_e);
}

// Round 7
// 234.575 us; speedup vs baseline: 2.0365x; 2.0365x over previous
//
#include <hip/hip_runtime.h>
#include <hip/hip_bf16.h>
#include <stdint.h>

#define B_ 1024
#define T_ 255
#define D_ 128

typedef float f32x4 __attribute__((ext_vector_type(4)));
typedef short s16x8 __attribute__((ext_vector_type(8)));
typedef unsigned u32x4 __attribute__((ext_vector_type(4)));

__device__ __forceinline__ unsigned pk2(float a, float b){
  __hip_bfloat162 h2 = __float22bfloat162_rn(make_float2(a, b));  // v_cvt_pk_bf16_f32
  union { __hip_bfloat162 h; unsigned u; } c; c.h = h2; return c.u;
}
__device__ __forceinline__ unsigned short bf1(float a){
  __hip_bfloat16 h = __float2bfloat16(a);
  union { __hip_bfloat16 h; unsigned short u; } c; c.h = h; return c.u;
}
__device__ __forceinline__ float sigm_f(float x){
  return __builtin_amdgcn_rcpf(1.f + __expf(-x));
}
__device__ __forceinline__ float tanh_f2(float x){
  return fmaf(-2.f, __builtin_amdgcn_rcpf(1.f + __expf(2.f * x)), 1.f);
}

// ---------------- Kernel 1: softmax(x_part) ; out_w = attn*x ; wx bf16 ----------
__global__ __launch_bounds__(512) void k_attn(const float* __restrict__ x,
    const float* __restrict__ Wa, float* __restrict__ out_w,
    uint2* __restrict__ wxq){
  extern __shared__ float4 xs4[];          // 8160 float4 = 130560 B
  __shared__ float wxs[256];
  __shared__ float part_s[16][128];
  __shared__ float red[128];
  __shared__ float attn_s[128];
  int tid = threadIdx.x, b = blockIdx.x;
  if (tid < T_) wxs[tid] = Wa[2 * D_ + tid];
  __syncthreads();
  const float4* xg = (const float4*)(x + (size_t)b * T_ * D_);
  float4 acc = {0.f, 0.f, 0.f, 0.f};
  for (int i = tid; i < 8160; i += 512){
    float4 v = xg[i];
    xs4[i] = v;
    float wt = wxs[i >> 5];
    acc.x += v.x * wt; acc.y += v.y * wt; acc.z += v.z * wt; acc.w += v.w * wt;
  }
  int d0 = (tid & 31) * 4, s = tid >> 5;
  *(float4*)&part_s[s][d0] = acc;
  __syncthreads();
  if (tid < 128){
    float v = 0.f;
    #pragma unroll
    for (int k = 0; k < 16; k++) v += part_s[k][tid];
    red[tid] = v; attn_s[tid] = v;
  }
  __syncthreads();
  for (int st = 64; st >= 1; st >>= 1){
    if (tid < st) red[tid] = fmaxf(red[tid], red[tid + st]);
    __syncthreads();
  }
  float mx = red[0];
  __syncthreads();
  float ev = 0.f;
  if (tid < 128){ ev = __expf(attn_s[tid] - mx); red[tid] = ev; }
  __syncthreads();
  for (int st = 64; st >= 1; st >>= 1){
    if (tid < st) red[tid] += red[tid + st];
    __syncthreads();
  }
  float sm = red[0];
  if (tid < 128) attn_s[tid] = ev / sm;
  __syncthreads();
  float4 at = *(const float4*)&attn_s[d0];
  float4* owg = (float4*)(out_w + (size_t)b * T_ * D_);
  for (int i = tid; i < 8160; i += 512){
    float4 v = xs4[i];
    float4 wv; wv.x = v.x*at.x; wv.y = v.y*at.y; wv.z = v.z*at.z; wv.w = v.w*at.w;
    owg[i] = wv;
    int t = i >> 5;
    uint2 q;
    q.x = pk2(wv.x, wv.y);
    q.y = pk2(wv.z, wv.w);
    wxq[((size_t)t * B_ + b) * 32 + (i & 31)] = q;   // [t][b][d] bf16 row-major
  }
}

// ---------------- Kernel 2: fused recurrence. 256 blocks x 4 rows x 512 thr -----
// r4-proven structure: wave w owns d-slice [16w,16w+16), all 4 gates, 1 cell/lane
// (owner = (row lg, d)). NEW: fih GEMM batched over 4 timesteps (A row l15 =
// (ts=l15>>2, br=l15&3), M=16 full) -> G1 f32 float4 {i,f,g,o} in LDS, wave-local.
// fhh per step: A row l15 = h row l15>>2 (x4 replication), C row lg*4+r -> acc[0].
__global__ __launch_bounds__(512, 2) void k_rnn(const float* __restrict__ W_ih,
    const float* __restrict__ W_hh, const float* __restrict__ b_ih,
    const float* __restrict__ b_hh, const unsigned short* __restrict__ wxb,
    float* __restrict__ out_e){
  __shared__ char hl[2048];      // h bf16 [buf][row 256B][slot 16B], slot^=(row&1)<<2
  __shared__ float4 g1l[2048];   // 32 KB f32 G1: [ts][br][d] -> (ts*4+br)*128+d
  int tid = threadIdx.x;
  int lane = tid & 63, w = tid >> 6;
  int l15 = lane & 15, lg = lane >> 4;
  int row0 = blockIdx.x << 2;
  int d = w * 16 + l15;
  int hr = l15 >> 2;             // h row this lane reads (x4 replication)

  // weight B-fragments [kt][gate], k = kt*32 + lg*8 + j
  s16x8 fih[4][4], fhh[4][4];
  float bias[4];
  #pragma unroll
  for (int g = 0; g < 4; g++){
    int n = g * 128 + w * 16 + l15;
    bias[g] = b_ih[n] + b_hh[n];
    #pragma unroll
    for (int kt = 0; kt < 4; kt++){
      const float4* p1 = (const float4*)(W_ih + n * D_ + kt * 32 + lg * 8);
      float4 a0 = p1[0], a1 = p1[1];
      u32x4 bv;
      bv[0] = pk2(a0.x, a0.y); bv[1] = pk2(a0.z, a0.w);
      bv[2] = pk2(a1.x, a1.y); bv[3] = pk2(a1.z, a1.w);
      fih[kt][g] = __builtin_bit_cast(s16x8, bv);
      const float4* p2 = (const float4*)(W_hh + n * D_ + kt * 32 + lg * 8);
      float4 c0v = p2[0], c1v = p2[1];
      u32x4 cv;
      cv[0] = pk2(c0v.x, c0v.y); cv[1] = pk2(c0v.z, c0v.w);
      cv[2] = pk2(c1v.x, c1v.y); cv[3] = pk2(c1v.z, c1v.w);
      fhh[kt][g] = __builtin_bit_cast(s16x8, cv);
    }
  }
  // h LDS addresses. Within-row 16B slot sigma = (k>>3) ^ ((row&1)<<2): the four
  // replicated rows split banks evenly (even rows: slots 0-3 region, odd: 4-7).
  unsigned rd_[4];
  #pragma unroll
  for (int kt = 0; kt < 4; kt++)
    rd_[kt] = (unsigned)(hr * 256 + (((kt << 2) + lg) ^ ((hr & 1) << 2)) * 16);
  unsigned wr_ = (unsigned)(lg * 256 + ((d >> 3) ^ ((lg & 1) << 2)) * 16 + (d & 7) * 2);

  float* op = out_e + (size_t)(row0 + lg) * T_ * D_ + d;
  float cst = 0.f;
  if (tid < 128) ((uint2*)hl)[tid] = make_uint2(0u, 0u);   // zero h buf0 (1 KB)

  // G1 float4 indices: write (ts=lg, br=r, d): lg*512 + r*128 + d
  //                    read  (ts=TS, br=lg, d): TS*512 + lg*128 + d
  int gw0 = lg * 512 + d;
  int gr0 = lg * 128 + d;

  // fih A stream: lane reads wx[t0 + (l15>>2)][row0 + (l15&3)][k-slice lg*8]
  const unsigned short* wp = wxb + ((size_t)(l15 >> 2) * B_ + row0 + (l15 & 3)) * D_ + lg * 8;
  const size_t GSTRIDE = (size_t)4 * B_ * D_;               // 4 timesteps
  s16x8 AF[4];
  #pragma unroll
  for (int kt = 0; kt < 4; kt++) AF[kt] = *(const s16x8*)(wp + kt * 32);
  wp += GSTRIDE;
  __syncthreads();

  // ---- batch-fih: 16 MFMA -> f32 G1 for 4 steps -> LDS (wave-local) ----
#define FIH_BATCH() do {                                                            \
    f32x4 bi = {bias[0], bias[0], bias[0], bias[0]};                                \
    f32x4 bf = {bias[1], bias[1], bias[1], bias[1]};                                \
    f32x4 bg = {bias[2], bias[2], bias[2], bias[2]};                                \
    f32x4 bo = {bias[3], bias[3], bias[3], bias[3]};                                \
    _Pragma("unroll")                                                               \
    for (int kt = 0; kt < 4; kt++){                                                 \
      bi = __builtin_amdgcn_mfma_f32_16x16x32_bf16(AF[kt], fih[kt][0], bi,0,0,0);   \
      bf = __builtin_amdgcn_mfma_f32_16x16x32_bf16(AF[kt], fih[kt][1], bf,0,0,0);   \
      bg = __builtin_amdgcn_mfma_f32_16x16x32_bf16(AF[kt], fih[kt][2], bg,0,0,0);   \
      bo = __builtin_amdgcn_mfma_f32_16x16x32_bf16(AF[kt], fih[kt][3], bo,0,0,0);   \
    }                                                                               \
    _Pragma("unroll")                                                               \
    for (int r = 0; r < 4; r++)                                                     \
      g1l[gw0 + r * 128] = make_float4(bi[r], bf[r], bg[r], bo[r]);                 \
  } while (0)

  // ---- one recurrence step (TS compile-time 0..3; h buf parity = TS&1) ----
#define STEP(TS) do {                                                               \
    s16x8 aa[4];                                                                    \
    _Pragma("unroll")                                                               \
    for (int kt = 0; kt < 4; kt++)                                                  \
      aa[kt] = *(const s16x8*)(hl + rd_[kt] + ((TS) & 1) * 1024);                   \
    f32x4 a0 = {0.f,0.f,0.f,0.f}, a1 = a0, a2 = a0, a3 = a0;                        \
    _Pragma("unroll")                                                               \
    for (int kt = 0; kt < 4; kt++){                                                 \
      a0 = __builtin_amdgcn_mfma_f32_16x16x32_bf16(aa[kt], fhh[kt][0], a0,0,0,0);   \
      a1 = __builtin_amdgcn_mfma_f32_16x16x32_bf16(aa[kt], fhh[kt][1], a1,0,0,0);   \
      a2 = __builtin_amdgcn_mfma_f32_16x16x32_bf16(aa[kt], fhh[kt][2], a2,0,0,0);   \
      a3 = __builtin_amdgcn_mfma_f32_16x16x32_bf16(aa[kt], fhh[kt][3], a3,0,0,0);   \
    }                                                                               \
    float4 q = g1l[gr0 + (TS) * 512];                                               \
    float gi = q.x + a0[0], gf = q.y + a1[0];                                       \
    float gg = q.z + a2[0], go = q.w + a3[0];                                       \
    float cn = fmaf(sigm_f(gf), cst, sigm_f(gi) * tanh_f2(gg));                     \
    float hn = sigm_f(go) * tanh_f2(cn); cst = cn;                                  \
    *op = hn; op += D_;                                                             \
    *(unsigned short*)(hl + wr_ + (1 - ((TS) & 1)) * 1024) = bf1(hn);               \
    __syncthreads();                                                                \
  } while (0)

  for (int g = 0; g < 63; g++){
    FIH_BATCH();
    #pragma unroll
    for (int kt = 0; kt < 4; kt++) AF[kt] = *(const s16x8*)(wp + kt * 32);
    wp += GSTRIDE;          // g=62 loads group 63 (t up to 255: zeroed pad slot)
    STEP(0); STEP(1); STEP(2); STEP(3);
  }
  // epilogue group: t = 252,253,254 (G1[ts=3] from zero pad, never read)
  FIH_BATCH();
  STEP(0); STEP(1); STEP(2);
#undef FIH_BATCH
#undef STEP
}

extern "C" void kernel_launch(void* const* d_in, const int* in_sizes, int n_in,
                              void* d_out, int out_size, void* d_ws, size_t ws_size,
                              hipStream_t stream) {
  (void)in_sizes; (void)n_in; (void)out_size;
  const float* x    = (const float*)d_in[0];
  const float* Wa   = (const float*)d_in[1];
  // d_in[2] = ba : dead (softmax shift invariance); Wh/Wc parts of Wa also dead
  const float* W_ih = (const float*)d_in[3];
  const float* W_hh = (const float*)d_in[4];
  const float* b_ih = (const float*)d_in[5];
  const float* b_hh = (const float*)d_in[6];
  float* out_w = (float*)d_out;
  float* out_e = out_w + (size_t)B_ * T_ * D_;
  unsigned short* wxb = (unsigned short*)d_ws;   // [t][b][d] bf16; T+1 slots
  size_t need = (size_t)(T_ + 1) * B_ * D_ * 2;  // 67.1 MB (t=255 pad, zeroed)
  if (ws_size < need) return;

  // zero the t=255 pad slot (prefetched by the last group, rows never read)
  hipMemsetAsync((char*)d_ws + (size_t)T_ * B_ * D_ * 2, 0, (size_t)B_ * D_ * 2, stream);
  k_attn<<<B_, 512, 130560, stream>>>(x, Wa, out_w, (uint2*)wxb);
  k_rnn <<<256, 512, 0, stream>>>(W_ih, W_hh, b_ih, b_hh, wxb, out_e);
}